// Round 16
// baseline (165.882 us; speedup 1.0000x reference)
//
#include <hip/hip_runtime.h>
#include <stdint.h>

typedef unsigned short u16;
typedef unsigned char u8;
typedef unsigned int u32;
typedef __attribute__((ext_vector_type(8))) short frag_ab;   // 8 bf16
typedef __attribute__((ext_vector_type(4))) float f32x4;

__device__ __forceinline__ u16 f2b(float f) {
  unsigned u = __float_as_uint(f);
  return (u16)((u + 0x7fffu + ((u >> 16) & 1u)) >> 16);
}
__device__ __forceinline__ float b2f(u16 u) {
  return __uint_as_float(((unsigned)u) << 16);
}

// ---- inline-asm loads: volatile => issued in order, never sunk to uses ----
__device__ __forceinline__ frag_ab gld16(const u16* p) {
  frag_ab d;
  asm volatile("global_load_dwordx4 %0, %1, off" : "=v"(d) : "v"(p));
  return d;
}
__device__ __forceinline__ u32 gld1(const u8* p) {
  u32 d;
  asm volatile("global_load_ubyte %0, %1, off" : "=v"(d) : "v"(p));
  return d;
}
__device__ __forceinline__ float gldf(const float* p) {
  float d;
  asm volatile("global_load_dword %0, %1, off" : "=v"(d) : "v"(p));
  return d;
}
__device__ __forceinline__ void wait_vm0() {
  asm volatile("s_waitcnt vmcnt(0)" ::: "memory");
  __builtin_amdgcn_sched_barrier(0);   // rule 18: pin uses below the wait
}

// all-wave inline int64 detection: odd int32 slots of first 64 elems all zero
__device__ __forceinline__ int detect64(const int* __restrict__ ei32) {
  int v = ei32[2 * (threadIdx.x & 63) + 1];
  unsigned long long b = __ballot(v == 0);
  return (b == ~0ULL) ? 1 : 0;
}

__device__ __forceinline__ int edge_at(const void* ei, long pos, int is64) {
  if (is64) return (int)((const long long*)ei)[pos];
  return ((const int*)ei)[pos];
}

// ---------------------------------------------------------------------------
// per-(chunk,bucket) histogram (bucket = row>>9) + fused convert:
//   xb = bf16(x)  (MFMA path, self-loop)      xq = fp8 e4m3(x)  (gather path)
__global__ __launch_bounds__(256) void k_bhist_cvt(
    const void* __restrict__ ei, int E, int CH, int NB, int NBpad,
    int* __restrict__ bh,
    const float* __restrict__ x, u16* __restrict__ xb, u8* __restrict__ xq,
    long n64) {
  __shared__ int cnt[512];
  const int k = blockIdx.x, tid = threadIdx.x;
  const int is64 = detect64((const int*)ei);
  for (long i = ((long)k * 256 + tid) * 8; i < n64; i += 65536L * 8) {
    float4 v0 = *(const float4*)(x + i);
    float4 v1 = *(const float4*)(x + i + 4);
    frag_ab o;
    o[0] = (short)f2b(v0.x); o[1] = (short)f2b(v0.y);
    o[2] = (short)f2b(v0.z); o[3] = (short)f2b(v0.w);
    o[4] = (short)f2b(v1.x); o[5] = (short)f2b(v1.y);
    o[6] = (short)f2b(v1.z); o[7] = (short)f2b(v1.w);
    *(frag_ab*)(xb + i) = o;
    u32 p0 = (u32)__builtin_amdgcn_cvt_pk_fp8_f32(v0.x, v0.y, 0, false);
    p0 = (u32)__builtin_amdgcn_cvt_pk_fp8_f32(v0.z, v0.w, (int)p0, true);
    u32 p1 = (u32)__builtin_amdgcn_cvt_pk_fp8_f32(v1.x, v1.y, 0, false);
    p1 = (u32)__builtin_amdgcn_cvt_pk_fp8_f32(v1.z, v1.w, (int)p1, true);
    *(uint2*)(xq + i) = make_uint2(p0, p1);
  }
  for (int t = tid; t < NB; t += 256) cnt[t] = 0;
  __syncthreads();
  int e0 = k * CH, e1 = min(E, e0 + CH);
  for (int e = e0 + tid; e < e1; e += 256)
    atomicAdd(&cnt[edge_at(ei, e, is64) >> 9], 1);
  __syncthreads();
  for (int t = tid; t < NB; t += 256) bh[k * NBpad + t] = cnt[t];
}

// bucket starts + in-place column prefix: bh[k][b] -> absolute staged offset
__global__ __launch_bounds__(256) void k_cscan(
    int* __restrict__ bh, int* __restrict__ bstart, int NB, int NBpad, int E) {
  __shared__ int s[256];
  const int b = threadIdx.x;
  int tot = 0;
  if (b < NB)
    for (int k = 0; k < 256; ++k) tot += bh[k * NBpad + b];
  s[b] = (b < NB) ? tot : 0;
  __syncthreads();
  for (int off = 1; off < 256; off <<= 1) {
    int u = (b >= off) ? s[b - off] : 0;
    __syncthreads();
    s[b] += u;
    __syncthreads();
  }
  int excl = s[b] - tot;
  if (b < NB) {
    bstart[b] = excl;
    int run = excl;
    for (int k = 0; k < 256; ++k) {
      int t = bh[k * NBpad + b];
      bh[k * NBpad + b] = run;
      run += t;
    }
  }
  if (b == 0) bstart[NB] = E;
}

// append edges to this chunk's reserved per-bucket runs; pack (row&511)<<23|col
__global__ __launch_bounds__(256) void k_partition(
    const void* __restrict__ ei, int E, int CH, int NB, int NBpad,
    const int* __restrict__ bh, u32* __restrict__ staged) {
  __shared__ int cur[512];
  const int k = blockIdx.x, tid = threadIdx.x;
  const int is64 = detect64((const int*)ei);
  for (int t = tid; t < NB; t += 256) cur[t] = bh[k * NBpad + t];
  __syncthreads();
  int e0 = k * CH, e1 = min(E, e0 + CH);
  for (int e = e0 + tid; e < e1; e += 256) {
    int r = edge_at(ei, e, is64);
    int c = edge_at(ei, (long)E + e, is64);
    int pos = atomicAdd(&cur[r >> 9], 1);
    staged[pos] = ((u32)(r & 511) << 23) | (u32)c;
  }
}

// one block per bucket: local degree histogram -> rowptr/dinv, then scatter
__global__ __launch_bounds__(1024) void k_csr_bucket(
    const u32* __restrict__ staged, const int* __restrict__ bstart,
    int* __restrict__ rowptr, float* __restrict__ dinv,
    u32* __restrict__ cols, int N, int E) {
  __shared__ int cnt[512];
  __shared__ int cur[512];
  const int b = blockIdx.x, tid = threadIdx.x;
  const int r0 = b << 9;
  if (tid < 512) cnt[tid] = 0;
  __syncthreads();
  const int j0 = bstart[b], j1 = bstart[b + 1];
  for (int j = j0 + tid; j < j1; j += 1024)
    atomicAdd(&cnt[staged[j] >> 23], 1);
  __syncthreads();
  if (tid < 512) cur[tid] = cnt[tid];
  __syncthreads();
  for (int off = 1; off < 512; off <<= 1) {
    int v = 0;
    if (tid < 512 && tid >= off) v = cur[tid - off];
    __syncthreads();
    if (tid < 512) cur[tid] += v;
    __syncthreads();
  }
  int myStart = 0;
  if (tid < 512) {
    myStart = j0 + cur[tid] - cnt[tid];
    int r = r0 + tid;
    if (r < N) {
      rowptr[r] = myStart;
      dinv[r] = rsqrtf((float)cnt[tid] + 1.0f);  // +1 = self loop
    }
  }
  __syncthreads();
  if (tid < 512) cur[tid] = myStart;
  if (b == 0 && tid == 0) rowptr[N] = E;
  __syncthreads();
  for (int j = j0 + tid; j < j1; j += 1024) {
    u32 v = staged[j];
    int rl = v >> 23;
    int pos = atomicAdd(&cur[rl], 1);
    cols[pos] = v & 0x7FFFFF;
  }
}

// TWO rows per wave; asm-batched fp8+dinv gathers (32 issued, one drain)
__global__ __launch_bounds__(256, 4) void k_aggregate(
    const int* __restrict__ rowptr, const u32* __restrict__ cols,
    const u16* __restrict__ xb, const u8* __restrict__ xq,
    const float* __restrict__ dinv, u16* __restrict__ aggb, int N) {
  int q = (blockIdx.x * 256 + threadIdx.x) >> 6;   // wave id
  int f = threadIdx.x & 63;
  int r0 = q * 2, r1 = q * 2 + 1;
  if (r0 >= N) return;
  const bool has1 = (r1 < N);
  int j0 = rowptr[r0], e0 = rowptr[r0 + 1];
  int j1 = has1 ? rowptr[r1] : 0;
  int e1 = has1 ? rowptr[r1 + 1] : 0;
  float d0 = dinv[r0];
  float d1 = has1 ? dinv[r1] : 0.f;
  float acc0 = b2f(xb[(long)r0 * 64 + f]) * d0;
  float acc1 = has1 ? b2f(xb[(long)r1 * 64 + f]) * d1 : 0.f;
  // main: 8+8 edges, 32 gathers in flight via asm, single drain
  while (j0 + 8 <= e0 && j1 + 8 <= e1) {
    int ca[8], cb[8];
#pragma unroll
    for (int i = 0; i < 8; ++i) { ca[i] = cols[j0 + i]; cb[i] = cols[j1 + i]; }
    u32 qa[8], qb[8];
    float wa[8], wb[8];
#pragma unroll
    for (int i = 0; i < 8; ++i) {
      qa[i] = gld1(xq + (long)ca[i] * 64 + f);
      qb[i] = gld1(xq + (long)cb[i] * 64 + f);
    }
#pragma unroll
    for (int i = 0; i < 8; ++i) {
      wa[i] = gldf(dinv + ca[i]);
      wb[i] = gldf(dinv + cb[i]);
    }
    wait_vm0();
#pragma unroll
    for (int i = 0; i < 8; ++i) {
      acc0 = fmaf(__builtin_amdgcn_cvt_f32_fp8((int)qa[i], 0), wa[i], acc0);
      acc1 = fmaf(__builtin_amdgcn_cvt_f32_fp8((int)qb[i], 0), wb[i], acc1);
    }
    j0 += 8; j1 += 8;
  }
  // dual 4-unroll, 16 gathers in flight
  while (j0 + 4 <= e0 && j1 + 4 <= e1) {
    int ca[4], cb[4];
#pragma unroll
    for (int i = 0; i < 4; ++i) { ca[i] = cols[j0 + i]; cb[i] = cols[j1 + i]; }
    u32 qa[4], qb[4];
    float wa[4], wb[4];
#pragma unroll
    for (int i = 0; i < 4; ++i) {
      qa[i] = gld1(xq + (long)ca[i] * 64 + f);
      qb[i] = gld1(xq + (long)cb[i] * 64 + f);
    }
#pragma unroll
    for (int i = 0; i < 4; ++i) {
      wa[i] = gldf(dinv + ca[i]);
      wb[i] = gldf(dinv + cb[i]);
    }
    wait_vm0();
#pragma unroll
    for (int i = 0; i < 4; ++i) {
      acc0 = fmaf(__builtin_amdgcn_cvt_f32_fp8((int)qa[i], 0), wa[i], acc0);
      acc1 = fmaf(__builtin_amdgcn_cvt_f32_fp8((int)qb[i], 0), wb[i], acc1);
    }
    j0 += 4; j1 += 4;
  }
  // row0 tail (asm batch of up to 4)
  for (; j0 + 4 <= e0; j0 += 4) {
    int c[4];
#pragma unroll
    for (int i = 0; i < 4; ++i) c[i] = cols[j0 + i];
    u32 qv[4]; float wv[4];
#pragma unroll
    for (int i = 0; i < 4; ++i) qv[i] = gld1(xq + (long)c[i] * 64 + f);
#pragma unroll
    for (int i = 0; i < 4; ++i) wv[i] = gldf(dinv + c[i]);
    wait_vm0();
#pragma unroll
    for (int i = 0; i < 4; ++i)
      acc0 = fmaf(__builtin_amdgcn_cvt_f32_fp8((int)qv[i], 0), wv[i], acc0);
  }
  for (; j0 < e0; ++j0) {
    int c = cols[j0];
    acc0 = fmaf(__builtin_amdgcn_cvt_f32_fp8((int)xq[(long)c * 64 + f], 0),
                dinv[c], acc0);
  }
  // row1 tail
  for (; j1 + 4 <= e1; j1 += 4) {
    int c[4];
#pragma unroll
    for (int i = 0; i < 4; ++i) c[i] = cols[j1 + i];
    u32 qv[4]; float wv[4];
#pragma unroll
    for (int i = 0; i < 4; ++i) qv[i] = gld1(xq + (long)c[i] * 64 + f);
#pragma unroll
    for (int i = 0; i < 4; ++i) wv[i] = gldf(dinv + c[i]);
    wait_vm0();
#pragma unroll
    for (int i = 0; i < 4; ++i)
      acc1 = fmaf(__builtin_amdgcn_cvt_f32_fp8((int)qv[i], 0), wv[i], acc1);
  }
  for (; j1 < e1; ++j1) {
    int c = cols[j1];
    acc1 = fmaf(__builtin_amdgcn_cvt_f32_fp8((int)xq[(long)c * 64 + f], 0),
                dinv[c], acc1);
  }
  aggb[(long)r0 * 64 + f] = f2b(acc0 * d0);
  if (has1) aggb[(long)r1 * 64 + f] = f2b(acc1 * d1);
}

// ---------------------------------------------------------------------------
// One-shot weight prep (unchanged)
// ---------------------------------------------------------------------------
__global__ __launch_bounds__(256) void k_wpack(
    const float* __restrict__ W1x, const float* __restrict__ W1a,
    const float* __restrict__ W2x, const float* __restrict__ W2a,
    const float* __restrict__ Wc, const float* __restrict__ b2x,
    const float* __restrict__ b2a, const float* __restrict__ bc,
    const float* __restrict__ Wcls,
    u16* __restrict__ W1xf, u16* __restrict__ W1af,
    u16* __restrict__ Wxpf, u16* __restrict__ Wapf,
    u16* __restrict__ Wclsf, float* __restrict__ bp) {
  const int blk = blockIdx.x, t = threadIdx.x;
  if (blk < 128) {
    const bool isX = blk < 64;
    int i = (isX ? blk : blk - 64) * 256 + t;        // packed index, K=128 Nc=128
    const float* W2 = isX ? W2x : W2a;
    const float* wc = isX ? Wc : Wc + 128 * 128;
    int b = i & 7, l = (i >> 3) & 63, fi = i >> 9;
    int kb = fi & 3, nb = fi >> 2;                   // KB = 4
    int k = kb * 32 + (l >> 4) * 8 + b;
    int n = nb * 16 + (l & 15);
    float s = 0.f;
    for (int m = 0; m < 128; ++m) s = fmaf(W2[k * 128 + m], wc[m * 128 + n], s);
    (isX ? Wxpf : Wapf)[i] = f2b(s);
  } else if (blk < 224) {
    const float* W; u16* dst; int K, Nc, i0;
    if (blk < 160)      { W = W1x;  dst = W1xf;  K = 64;  Nc = 128; i0 = blk - 128; }
    else if (blk < 192) { W = W1a;  dst = W1af;  K = 64;  Nc = 128; i0 = blk - 160; }
    else                { W = Wcls; dst = Wclsf; K = 128; Nc = 64;  i0 = blk - 192; }
    int i = i0 * 256 + t;
    if (i < K * Nc) {
      int b = i & 7, l = (i >> 3) & 63, fi = i >> 9;
      int KB = K >> 5;
      int kb = fi % KB, nb = fi / KB;
      int k = kb * 32 + (l >> 4) * 8 + b;
      int n = nb * 16 + (l & 15);
      dst[i] = f2b(W[k * Nc + n]);
    }
  } else if (t < 128) {
    float s = bc[t];
    for (int m = 0; m < 128; ++m)
      s += b2x[m] * Wc[m * 128 + t] + b2a[m] * Wc[(128 + m) * 128 + t];
    bp[t] = s;
  }
}

// ---------------------------------------------------------------------------
// Fused MLP v7: R12 structure + ASM batch-issued B/A loads with one
// vmcnt(0) drain per batch (loads cannot be sunk -> one latency per batch).
// ---------------------------------------------------------------------------
__global__ __launch_bounds__(256, 2) void k_mlp(
    const u16* __restrict__ xb, const u16* __restrict__ aggb,
    const u16* __restrict__ W1xf, const u16* __restrict__ W1af,
    const float* __restrict__ b1x, const float* __restrict__ b1a,
    const u16* __restrict__ Wxpf, const u16* __restrict__ Wapf,
    const float* __restrict__ bp,
    const u16* __restrict__ Wclsf, const float* __restrict__ bcls,
    float* __restrict__ out, int N) {
  __shared__ u16 S[4][16 * 256];    // 32KB total; per-wave 8KB slice
  const int w = threadIdx.x >> 6;
  const int lane = threadIdx.x & 63;
  const int m0 = blockIdx.x * 64 + w * 16;
  const int lm = lane & 15;
  const int lq = lane >> 4;
  u16* s = S[w];

  // ---- phase 1: s[row*256+col] = relu([x|agg]@W1+b1), swizzled
  for (int br = 0; br < 2; ++br) {
    const u16* A = br ? aggb : xb;
    const u16* Wf = br ? W1af : W1xf;
    const float* bias = br ? b1a : b1x;
    const u16* ap = A + (long)(m0 + lm) * 64 + lq * 8;
    frag_ab a0 = gld16(ap);
    frag_ab a1 = gld16(ap + 32);
    frag_ab B1[16];
#pragma unroll
    for (int i = 0; i < 16; ++i)
      B1[i] = gld16(Wf + (size_t)(i * 64 + lane) * 8);
    wait_vm0();                       // 18 loads, one drain
#pragma unroll
    for (int nb = 0; nb < 8; ++nb) {
      f32x4 acc = {0.f, 0.f, 0.f, 0.f};
      acc = __builtin_amdgcn_mfma_f32_16x16x32_bf16(a0, B1[nb * 2], acc, 0, 0, 0);
      acc = __builtin_amdgcn_mfma_f32_16x16x32_bf16(a1, B1[nb * 2 + 1], acc, 0, 0, 0);
      int col = nb * 16 + lm;
      float bv = bias[col];
#pragma unroll
      for (int r = 0; r < 4; ++r) {
        int row = lq * 4 + r;
        s[(row * 256 + br * 128 + col) ^ ((row & 7) << 3)] =
            f2b(fmaxf(acc[r] + bv, 0.f));
      }
    }
  }
  __builtin_amdgcn_wave_barrier();

  // ---- phase 2: read full H1 fragment set into regs, then H2 overwrites
  // the head of the slice (per-wave DS queue is in-order).
  frag_ab hfr[8];
#pragma unroll
  for (int kb = 0; kb < 8; ++kb)
    hfr[kb] = *(const frag_ab*)&s[(lm * 256 + kb * 32 + lq * 8) ^ ((lm & 7) << 3)];
  __builtin_amdgcn_wave_barrier();
#pragma unroll
  for (int nbp = 0; nbp < 4; ++nbp) {          // 4 batches x 16 loads
    frag_ab B2[16];
#pragma unroll
    for (int h = 0; h < 2; ++h) {
      int nb = nbp * 2 + h;
#pragma unroll
      for (int kb = 0; kb < 8; ++kb) {
        const u16* Wf2 = (kb < 4) ? Wxpf : Wapf;
        B2[h * 8 + kb] = gld16(Wf2 + (size_t)((nb * 4 + (kb & 3)) * 64 + lane) * 8);
      }
    }
    wait_vm0();                     // 16 loads, one drain
#pragma unroll
    for (int h = 0; h < 2; ++h) {
      int nb = nbp * 2 + h;
      f32x4 acc = {0.f, 0.f, 0.f, 0.f};
#pragma unroll
      for (int kb = 0; kb < 8; ++kb)
        acc = __builtin_amdgcn_mfma_f32_16x16x32_bf16(hfr[kb], B2[h * 8 + kb], acc, 0, 0, 0);
      int col = nb * 16 + lm;
      float bv = bp[col];
#pragma unroll
      for (int r = 0; r < 4; ++r) {
        int row = lq * 4 + r;
        s[(row * 128 + col) ^ ((row & 7) << 3)] = f2b(fmaxf(acc[r] + bv, 0.f));
      }
    }
  }
  __builtin_amdgcn_wave_barrier();

  // ---- phase 3: out = H2 @ Wcls + bcls, K=128
  frag_ab h3[4];
#pragma unroll
  for (int kb = 0; kb < 4; ++kb)
    h3[kb] = *(const frag_ab*)&s[(lm * 128 + kb * 32 + lq * 8) ^ ((lm & 7) << 3)];
  frag_ab B3[16];
#pragma unroll
  for (int i = 0; i < 16; ++i)
    B3[i] = gld16(Wclsf + (size_t)(i * 64 + lane) * 8);
  wait_vm0();                       // 16 loads, one drain
#pragma unroll
  for (int nb = 0; nb < 4; ++nb) {
    f32x4 acc = {0.f, 0.f, 0.f, 0.f};
#pragma unroll
    for (int kb = 0; kb < 4; ++kb)
      acc = __builtin_amdgcn_mfma_f32_16x16x32_bf16(h3[kb], B3[nb * 4 + kb], acc, 0, 0, 0);
    int col = nb * 16 + lm;
    float bv = bcls[col];
#pragma unroll
    for (int r = 0; r < 4; ++r) {
      int grow = m0 + lq * 4 + r;
      if (grow < N) out[(long)grow * 64 + col] = acc[r] + bv;
    }
  }
}

extern "C" void kernel_launch(void* const* d_in, const int* in_sizes, int n_in,
                              void* d_out, int out_size, void* d_ws, size_t ws_size,
                              hipStream_t stream) {
  const float* x    = (const float*)d_in[0];
  const void*  ei   = d_in[1];
  const float* W1x  = (const float*)d_in[2];
  const float* b1x  = (const float*)d_in[3];
  const float* W2x  = (const float*)d_in[4];
  const float* b2x  = (const float*)d_in[5];
  const float* W1a  = (const float*)d_in[6];
  const float* b1a  = (const float*)d_in[7];
  const float* W2a  = (const float*)d_in[8];
  const float* b2a  = (const float*)d_in[9];
  const float* Wc   = (const float*)d_in[10];
  const float* bc   = (const float*)d_in[11];
  const float* Wcls = (const float*)d_in[12];
  const float* bcls = (const float*)d_in[13];
  const int N = in_sizes[0] / 64;
  const int E = in_sizes[1] / 2;

  const int NB = (N + 511) >> 9;          // 512 rows per bucket
  const int NBpad = (NB + 63) & ~63;
  const int CH = (E + 255) / 256;

  float* ws = (float*)d_ws;
  long nAlign = (N + 255) & ~255L;
  float* dinv = ws;                                    // N
  int*   rowptr = (int*)(ws + nAlign);                 // N+1
  u16*   xb   = (u16*)(ws + 2 * nAlign + 256);         // N*64 bf16
  u16*   aggb = xb + (long)N * 64;                     // N*64 bf16
  u8*    xq   = (u8*)(aggb + (long)N * 64);            // N*64 fp8
  float* bp   = (float*)(xq + ((long)N * 64 + 255 & ~255L));  // 128
  u16*   W1xf = (u16*)(bp + 128);                      // 8192
  u16*   W1af = W1xf + 8192;                           // 8192
  u16*   Wxpf = W1af + 8192;                           // 16384
  u16*   Wapf = Wxpf + 16384;                          // 16384
  u16*   Wclsf = Wapf + 16384;                         // 8192
  int*   bh   = (int*)(Wclsf + 8192);                  // 256*NBpad
  int*   bstart = bh + 256 * NBpad;                    // NB+1 (+pad)
  u32*   staged = (u32*)(bstart + NB + 64);            // E
  u32*   cols   = staged + E;                          // E
  float* out = (float*)d_out;

  k_bhist_cvt<<<256, 256, 0, stream>>>(ei, E, CH, NB, NBpad, bh, x, xb, xq,
                                       (long)N * 64);
  k_cscan<<<1, 256, 0, stream>>>(bh, bstart, NB, NBpad, E);
  k_partition<<<256, 256, 0, stream>>>(ei, E, CH, NB, NBpad, bh, staged);
  k_csr_bucket<<<NB, 1024, 0, stream>>>(staged, bstart, rowptr, dinv, cols, N, E);
  k_aggregate<<<(N + 7) / 8, 256, 0, stream>>>(rowptr, cols, xb, xq, dinv, aggb, N);
  k_wpack<<<225, 256, 0, stream>>>(W1x, W1a, W2x, W2a, Wc, b2x, b2a, bc, Wcls,
                                   W1xf, W1af, Wxpf, Wapf, Wclsf, bp);
  k_mlp<<<(N + 63) / 64, 256, 0, stream>>>(xb, aggb, W1xf, W1af, b1x, b1a,
                                           Wxpf, Wapf, bp, Wclsf, bcls, out, N);
}

// Round 17
// 152.755 us; speedup vs baseline: 1.0859x; 1.0859x over previous
//
#include <hip/hip_runtime.h>
#include <stdint.h>

typedef unsigned short u16;
typedef unsigned char u8;
typedef unsigned int u32;
typedef __attribute__((ext_vector_type(8))) short frag_ab;   // 8 bf16
typedef __attribute__((ext_vector_type(4))) float f32x4;

__device__ __forceinline__ u16 f2b(float f) {
  unsigned u = __float_as_uint(f);
  return (u16)((u + 0x7fffu + ((u >> 16) & 1u)) >> 16);
}
__device__ __forceinline__ float b2f(u16 u) {
  return __uint_as_float(((unsigned)u) << 16);
}

// ---- inline-asm loads (k_mlp only): volatile => issued in order ----
__device__ __forceinline__ frag_ab gld16(const u16* p) {
  frag_ab d;
  asm volatile("global_load_dwordx4 %0, %1, off" : "=v"(d) : "v"(p));
  return d;
}
__device__ __forceinline__ void wait_vm0() {
  asm volatile("s_waitcnt vmcnt(0)" ::: "memory");
  __builtin_amdgcn_sched_barrier(0);   // rule 18: pin uses below the wait
}

// all-wave inline int64 detection: odd int32 slots of first 64 elems all zero
__device__ __forceinline__ int detect64(const int* __restrict__ ei32) {
  int v = ei32[2 * (threadIdx.x & 63) + 1];
  unsigned long long b = __ballot(v == 0);
  return (b == ~0ULL) ? 1 : 0;
}

__device__ __forceinline__ int edge_at(const void* ei, long pos, int is64) {
  if (is64) return (int)((const long long*)ei)[pos];
  return ((const int*)ei)[pos];
}

// ---------------------------------------------------------------------------
// per-(chunk,bucket) histogram (bucket = row>>9) + fused convert:
//   xb = bf16(x)  (MFMA path, self-loop)      xq = fp8 e4m3(x)  (gather path)
__global__ __launch_bounds__(256) void k_bhist_cvt(
    const void* __restrict__ ei, int E, int CH, int NB, int NBpad,
    int* __restrict__ bh,
    const float* __restrict__ x, u16* __restrict__ xb, u8* __restrict__ xq,
    long n64) {
  __shared__ int cnt[512];
  const int k = blockIdx.x, tid = threadIdx.x;
  const int is64 = detect64((const int*)ei);
  for (long i = ((long)k * 256 + tid) * 8; i < n64; i += 65536L * 8) {
    float4 v0 = *(const float4*)(x + i);
    float4 v1 = *(const float4*)(x + i + 4);
    frag_ab o;
    o[0] = (short)f2b(v0.x); o[1] = (short)f2b(v0.y);
    o[2] = (short)f2b(v0.z); o[3] = (short)f2b(v0.w);
    o[4] = (short)f2b(v1.x); o[5] = (short)f2b(v1.y);
    o[6] = (short)f2b(v1.z); o[7] = (short)f2b(v1.w);
    *(frag_ab*)(xb + i) = o;
    u32 p0 = (u32)__builtin_amdgcn_cvt_pk_fp8_f32(v0.x, v0.y, 0, false);
    p0 = (u32)__builtin_amdgcn_cvt_pk_fp8_f32(v0.z, v0.w, (int)p0, true);
    u32 p1 = (u32)__builtin_amdgcn_cvt_pk_fp8_f32(v1.x, v1.y, 0, false);
    p1 = (u32)__builtin_amdgcn_cvt_pk_fp8_f32(v1.z, v1.w, (int)p1, true);
    *(uint2*)(xq + i) = make_uint2(p0, p1);
  }
  for (int t = tid; t < NB; t += 256) cnt[t] = 0;
  __syncthreads();
  int e0 = k * CH, e1 = min(E, e0 + CH);
  for (int e = e0 + tid; e < e1; e += 256)
    atomicAdd(&cnt[edge_at(ei, e, is64) >> 9], 1);
  __syncthreads();
  for (int t = tid; t < NB; t += 256) bh[k * NBpad + t] = cnt[t];
}

// bucket starts + in-place column prefix: bh[k][b] -> absolute staged offset
__global__ __launch_bounds__(256) void k_cscan(
    int* __restrict__ bh, int* __restrict__ bstart, int NB, int NBpad, int E) {
  __shared__ int s[256];
  const int b = threadIdx.x;
  int tot = 0;
  if (b < NB)
    for (int k = 0; k < 256; ++k) tot += bh[k * NBpad + b];
  s[b] = (b < NB) ? tot : 0;
  __syncthreads();
  for (int off = 1; off < 256; off <<= 1) {
    int u = (b >= off) ? s[b - off] : 0;
    __syncthreads();
    s[b] += u;
    __syncthreads();
  }
  int excl = s[b] - tot;
  if (b < NB) {
    bstart[b] = excl;
    int run = excl;
    for (int k = 0; k < 256; ++k) {
      int t = bh[k * NBpad + b];
      bh[k * NBpad + b] = run;
      run += t;
    }
  }
  if (b == 0) bstart[NB] = E;
}

// append edges to this chunk's reserved per-bucket runs; pack (row&511)<<23|col
__global__ __launch_bounds__(256) void k_partition(
    const void* __restrict__ ei, int E, int CH, int NB, int NBpad,
    const int* __restrict__ bh, u32* __restrict__ staged) {
  __shared__ int cur[512];
  const int k = blockIdx.x, tid = threadIdx.x;
  const int is64 = detect64((const int*)ei);
  for (int t = tid; t < NB; t += 256) cur[t] = bh[k * NBpad + t];
  __syncthreads();
  int e0 = k * CH, e1 = min(E, e0 + CH);
  for (int e = e0 + tid; e < e1; e += 256) {
    int r = edge_at(ei, e, is64);
    int c = edge_at(ei, (long)E + e, is64);
    int pos = atomicAdd(&cur[r >> 9], 1);
    staged[pos] = ((u32)(r & 511) << 23) | (u32)c;
  }
}

// one block per bucket: local degree histogram -> rowptr/dinv, then scatter
__global__ __launch_bounds__(1024) void k_csr_bucket(
    const u32* __restrict__ staged, const int* __restrict__ bstart,
    int* __restrict__ rowptr, float* __restrict__ dinv,
    u32* __restrict__ cols, int N, int E) {
  __shared__ int cnt[512];
  __shared__ int cur[512];
  const int b = blockIdx.x, tid = threadIdx.x;
  const int r0 = b << 9;
  if (tid < 512) cnt[tid] = 0;
  __syncthreads();
  const int j0 = bstart[b], j1 = bstart[b + 1];
  for (int j = j0 + tid; j < j1; j += 1024)
    atomicAdd(&cnt[staged[j] >> 23], 1);
  __syncthreads();
  if (tid < 512) cur[tid] = cnt[tid];
  __syncthreads();
  for (int off = 1; off < 512; off <<= 1) {
    int v = 0;
    if (tid < 512 && tid >= off) v = cur[tid - off];
    __syncthreads();
    if (tid < 512) cur[tid] += v;
    __syncthreads();
  }
  int myStart = 0;
  if (tid < 512) {
    myStart = j0 + cur[tid] - cnt[tid];
    int r = r0 + tid;
    if (r < N) {
      rowptr[r] = myStart;
      dinv[r] = rsqrtf((float)cnt[tid] + 1.0f);  // +1 = self loop
    }
  }
  __syncthreads();
  if (tid < 512) cur[tid] = myStart;
  if (b == 0 && tid == 0) rowptr[N] = E;
  __syncthreads();
  for (int j = j0 + tid; j < j1; j += 1024) {
    u32 v = staged[j];
    int rl = v >> 23;
    int pos = atomicAdd(&cur[rl], 1);
    cols[pos] = v & 0x7FFFFF;
  }
}

// TWO rows per wave, plain loads (R15 version — measured floor ~46us:
// 0.9M L2-miss lines / 256 CU / ~16 outstanding x ~450cy L3 = 41us model)
__global__ __launch_bounds__(256, 4) void k_aggregate(
    const int* __restrict__ rowptr, const u32* __restrict__ cols,
    const u16* __restrict__ xb, const u8* __restrict__ xq,
    const float* __restrict__ dinv, u16* __restrict__ aggb, int N) {
  int q = (blockIdx.x * 256 + threadIdx.x) >> 6;   // wave id
  int f = threadIdx.x & 63;
  int r0 = q * 2, r1 = q * 2 + 1;
  if (r0 >= N) return;
  const bool has1 = (r1 < N);
  int j0 = rowptr[r0], e0 = rowptr[r0 + 1];
  int j1 = has1 ? rowptr[r1] : 0;
  int e1 = has1 ? rowptr[r1 + 1] : 0;
  float d0 = dinv[r0];
  float d1 = has1 ? dinv[r1] : 0.f;
  float acc0 = b2f(xb[(long)r0 * 64 + f]) * d0;
  float acc1 = has1 ? b2f(xb[(long)r1 * 64 + f]) * d1 : 0.f;
  // main: 8+8 edges in flight
  while (j0 + 8 <= e0 && j1 + 8 <= e1) {
    int ca[8], cb[8];
#pragma unroll
    for (int i = 0; i < 8; ++i) { ca[i] = cols[j0 + i]; cb[i] = cols[j1 + i]; }
    int qa[8], qb[8];
    float wa[8], wb[8];
#pragma unroll
    for (int i = 0; i < 8; ++i) {
      qa[i] = xq[(long)ca[i] * 64 + f];
      qb[i] = xq[(long)cb[i] * 64 + f];
      wa[i] = dinv[ca[i]];
      wb[i] = dinv[cb[i]];
    }
    __builtin_amdgcn_sched_barrier(0);
#pragma unroll
    for (int i = 0; i < 8; ++i) {
      acc0 = fmaf(__builtin_amdgcn_cvt_f32_fp8(qa[i], 0), wa[i], acc0);
      acc1 = fmaf(__builtin_amdgcn_cvt_f32_fp8(qb[i], 0), wb[i], acc1);
    }
    j0 += 8; j1 += 8;
  }
  // dual 4-unroll
  while (j0 + 4 <= e0 && j1 + 4 <= e1) {
    int ca[4], cb[4];
#pragma unroll
    for (int i = 0; i < 4; ++i) { ca[i] = cols[j0 + i]; cb[i] = cols[j1 + i]; }
    int qa[4], qb[4];
    float wa[4], wb[4];
#pragma unroll
    for (int i = 0; i < 4; ++i) {
      qa[i] = xq[(long)ca[i] * 64 + f];
      qb[i] = xq[(long)cb[i] * 64 + f];
      wa[i] = dinv[ca[i]];
      wb[i] = dinv[cb[i]];
    }
    __builtin_amdgcn_sched_barrier(0);
#pragma unroll
    for (int i = 0; i < 4; ++i) {
      acc0 = fmaf(__builtin_amdgcn_cvt_f32_fp8(qa[i], 0), wa[i], acc0);
      acc1 = fmaf(__builtin_amdgcn_cvt_f32_fp8(qb[i], 0), wb[i], acc1);
    }
    j0 += 4; j1 += 4;
  }
  // row0 tail
  for (; j0 + 4 <= e0; j0 += 4) {
    int c0 = cols[j0], c1 = cols[j0 + 1], c2 = cols[j0 + 2], c3 = cols[j0 + 3];
    int q0 = xq[(long)c0 * 64 + f];
    int q1 = xq[(long)c1 * 64 + f];
    int q2 = xq[(long)c2 * 64 + f];
    int q3 = xq[(long)c3 * 64 + f];
    acc0 = fmaf(__builtin_amdgcn_cvt_f32_fp8(q0, 0), dinv[c0], acc0);
    acc0 = fmaf(__builtin_amdgcn_cvt_f32_fp8(q1, 0), dinv[c1], acc0);
    acc0 = fmaf(__builtin_amdgcn_cvt_f32_fp8(q2, 0), dinv[c2], acc0);
    acc0 = fmaf(__builtin_amdgcn_cvt_f32_fp8(q3, 0), dinv[c3], acc0);
  }
  for (; j0 < e0; ++j0) {
    int c = cols[j0];
    acc0 = fmaf(__builtin_amdgcn_cvt_f32_fp8((int)xq[(long)c * 64 + f], 0),
                dinv[c], acc0);
  }
  // row1 tail
  for (; j1 + 4 <= e1; j1 += 4) {
    int c0 = cols[j1], c1 = cols[j1 + 1], c2 = cols[j1 + 2], c3 = cols[j1 + 3];
    int q0 = xq[(long)c0 * 64 + f];
    int q1 = xq[(long)c1 * 64 + f];
    int q2 = xq[(long)c2 * 64 + f];
    int q3 = xq[(long)c3 * 64 + f];
    acc1 = fmaf(__builtin_amdgcn_cvt_f32_fp8(q0, 0), dinv[c0], acc1);
    acc1 = fmaf(__builtin_amdgcn_cvt_f32_fp8(q1, 0), dinv[c1], acc1);
    acc1 = fmaf(__builtin_amdgcn_cvt_f32_fp8(q2, 0), dinv[c2], acc1);
    acc1 = fmaf(__builtin_amdgcn_cvt_f32_fp8(q3, 0), dinv[c3], acc1);
  }
  for (; j1 < e1; ++j1) {
    int c = cols[j1];
    acc1 = fmaf(__builtin_amdgcn_cvt_f32_fp8((int)xq[(long)c * 64 + f], 0),
                dinv[c], acc1);
  }
  aggb[(long)r0 * 64 + f] = f2b(acc0 * d0);
  if (has1) aggb[(long)r1 * 64 + f] = f2b(acc1 * d1);
}

// ---------------------------------------------------------------------------
// One-shot weight prep (unchanged)
// ---------------------------------------------------------------------------
__global__ __launch_bounds__(256) void k_wpack(
    const float* __restrict__ W1x, const float* __restrict__ W1a,
    const float* __restrict__ W2x, const float* __restrict__ W2a,
    const float* __restrict__ Wc, const float* __restrict__ b2x,
    const float* __restrict__ b2a, const float* __restrict__ bc,
    const float* __restrict__ Wcls,
    u16* __restrict__ W1xf, u16* __restrict__ W1af,
    u16* __restrict__ Wxpf, u16* __restrict__ Wapf,
    u16* __restrict__ Wclsf, float* __restrict__ bp) {
  const int blk = blockIdx.x, t = threadIdx.x;
  if (blk < 128) {
    const bool isX = blk < 64;
    int i = (isX ? blk : blk - 64) * 256 + t;        // packed index, K=128 Nc=128
    const float* W2 = isX ? W2x : W2a;
    const float* wc = isX ? Wc : Wc + 128 * 128;
    int b = i & 7, l = (i >> 3) & 63, fi = i >> 9;
    int kb = fi & 3, nb = fi >> 2;                   // KB = 4
    int k = kb * 32 + (l >> 4) * 8 + b;
    int n = nb * 16 + (l & 15);
    float s = 0.f;
    for (int m = 0; m < 128; ++m) s = fmaf(W2[k * 128 + m], wc[m * 128 + n], s);
    (isX ? Wxpf : Wapf)[i] = f2b(s);
  } else if (blk < 224) {
    const float* W; u16* dst; int K, Nc, i0;
    if (blk < 160)      { W = W1x;  dst = W1xf;  K = 64;  Nc = 128; i0 = blk - 128; }
    else if (blk < 192) { W = W1a;  dst = W1af;  K = 64;  Nc = 128; i0 = blk - 160; }
    else                { W = Wcls; dst = Wclsf; K = 128; Nc = 64;  i0 = blk - 192; }
    int i = i0 * 256 + t;
    if (i < K * Nc) {
      int b = i & 7, l = (i >> 3) & 63, fi = i >> 9;
      int KB = K >> 5;
      int kb = fi % KB, nb = fi / KB;
      int k = kb * 32 + (l >> 4) * 8 + b;
      int n = nb * 16 + (l & 15);
      dst[i] = f2b(W[k * Nc + n]);
    }
  } else if (t < 128) {
    float s = bc[t];
    for (int m = 0; m < 128; ++m)
      s += b2x[m] * Wc[m * 128 + t] + b2a[m] * Wc[(128 + m) * 128 + t];
    bp[t] = s;
  }
}

// ---------------------------------------------------------------------------
// Fused MLP v7 (R16 version, kept): asm batch-issued B/A loads with one
// vmcnt(0) drain per batch.
// ---------------------------------------------------------------------------
__global__ __launch_bounds__(256, 2) void k_mlp(
    const u16* __restrict__ xb, const u16* __restrict__ aggb,
    const u16* __restrict__ W1xf, const u16* __restrict__ W1af,
    const float* __restrict__ b1x, const float* __restrict__ b1a,
    const u16* __restrict__ Wxpf, const u16* __restrict__ Wapf,
    const float* __restrict__ bp,
    const u16* __restrict__ Wclsf, const float* __restrict__ bcls,
    float* __restrict__ out, int N) {
  __shared__ u16 S[4][16 * 256];    // 32KB total; per-wave 8KB slice
  const int w = threadIdx.x >> 6;
  const int lane = threadIdx.x & 63;
  const int m0 = blockIdx.x * 64 + w * 16;
  const int lm = lane & 15;
  const int lq = lane >> 4;
  u16* s = S[w];

  // ---- phase 1: s[row*256+col] = relu([x|agg]@W1+b1), swizzled
  for (int br = 0; br < 2; ++br) {
    const u16* A = br ? aggb : xb;
    const u16* Wf = br ? W1af : W1xf;
    const float* bias = br ? b1a : b1x;
    const u16* ap = A + (long)(m0 + lm) * 64 + lq * 8;
    frag_ab a0 = gld16(ap);
    frag_ab a1 = gld16(ap + 32);
    frag_ab B1[16];
#pragma unroll
    for (int i = 0; i < 16; ++i)
      B1[i] = gld16(Wf + (size_t)(i * 64 + lane) * 8);
    wait_vm0();                       // 18 loads, one drain
#pragma unroll
    for (int nb = 0; nb < 8; ++nb) {
      f32x4 acc = {0.f, 0.f, 0.f, 0.f};
      acc = __builtin_amdgcn_mfma_f32_16x16x32_bf16(a0, B1[nb * 2], acc, 0, 0, 0);
      acc = __builtin_amdgcn_mfma_f32_16x16x32_bf16(a1, B1[nb * 2 + 1], acc, 0, 0, 0);
      int col = nb * 16 + lm;
      float bv = bias[col];
#pragma unroll
      for (int r = 0; r < 4; ++r) {
        int row = lq * 4 + r;
        s[(row * 256 + br * 128 + col) ^ ((row & 7) << 3)] =
            f2b(fmaxf(acc[r] + bv, 0.f));
      }
    }
  }
  __builtin_amdgcn_wave_barrier();

  // ---- phase 2: read full H1 fragment set into regs, then H2 overwrites
  // the head of the slice (per-wave DS queue is in-order).
  frag_ab hfr[8];
#pragma unroll
  for (int kb = 0; kb < 8; ++kb)
    hfr[kb] = *(const frag_ab*)&s[(lm * 256 + kb * 32 + lq * 8) ^ ((lm & 7) << 3)];
  __builtin_amdgcn_wave_barrier();
#pragma unroll
  for (int nbp = 0; nbp < 4; ++nbp) {          // 4 batches x 16 loads
    frag_ab B2[16];
#pragma unroll
    for (int h = 0; h < 2; ++h) {
      int nb = nbp * 2 + h;
#pragma unroll
      for (int kb = 0; kb < 8; ++kb) {
        const u16* Wf2 = (kb < 4) ? Wxpf : Wapf;
        B2[h * 8 + kb] = gld16(Wf2 + (size_t)((nb * 4 + (kb & 3)) * 64 + lane) * 8);
      }
    }
    wait_vm0();                     // 16 loads, one drain
#pragma unroll
    for (int h = 0; h < 2; ++h) {
      int nb = nbp * 2 + h;
      f32x4 acc = {0.f, 0.f, 0.f, 0.f};
#pragma unroll
      for (int kb = 0; kb < 8; ++kb)
        acc = __builtin_amdgcn_mfma_f32_16x16x32_bf16(hfr[kb], B2[h * 8 + kb], acc, 0, 0, 0);
      int col = nb * 16 + lm;
      float bv = bp[col];
#pragma unroll
      for (int r = 0; r < 4; ++r) {
        int row = lq * 4 + r;
        s[(row * 128 + col) ^ ((row & 7) << 3)] = f2b(fmaxf(acc[r] + bv, 0.f));
      }
    }
  }
  __builtin_amdgcn_wave_barrier();

  // ---- phase 3: out = H2 @ Wcls + bcls, K=128
  frag_ab h3[4];
#pragma unroll
  for (int kb = 0; kb < 4; ++kb)
    h3[kb] = *(const frag_ab*)&s[(lm * 128 + kb * 32 + lq * 8) ^ ((lm & 7) << 3)];
  frag_ab B3[16];
#pragma unroll
  for (int i = 0; i < 16; ++i)
    B3[i] = gld16(Wclsf + (size_t)(i * 64 + lane) * 8);
  wait_vm0();                       // 16 loads, one drain
#pragma unroll
  for (int nb = 0; nb < 4; ++nb) {
    f32x4 acc = {0.f, 0.f, 0.f, 0.f};
#pragma unroll
    for (int kb = 0; kb < 4; ++kb)
      acc = __builtin_amdgcn_mfma_f32_16x16x32_bf16(h3[kb], B3[nb * 4 + kb], acc, 0, 0, 0);
    int col = nb * 16 + lm;
    float bv = bcls[col];
#pragma unroll
    for (int r = 0; r < 4; ++r) {
      int grow = m0 + lq * 4 + r;
      if (grow < N) out[(long)grow * 64 + col] = acc[r] + bv;
    }
  }
}

extern "C" void kernel_launch(void* const* d_in, const int* in_sizes, int n_in,
                              void* d_out, int out_size, void* d_ws, size_t ws_size,
                              hipStream_t stream) {
  const float* x    = (const float*)d_in[0];
  const void*  ei   = d_in[1];
  const float* W1x  = (const float*)d_in[2];
  const float* b1x  = (const float*)d_in[3];
  const float* W2x  = (const float*)d_in[4];
  const float* b2x  = (const float*)d_in[5];
  const float* W1a  = (const float*)d_in[6];
  const float* b1a  = (const float*)d_in[7];
  const float* W2a  = (const float*)d_in[8];
  const float* b2a  = (const float*)d_in[9];
  const float* Wc   = (const float*)d_in[10];
  const float* bc   = (const float*)d_in[11];
  const float* Wcls = (const float*)d_in[12];
  const float* bcls = (const float*)d_in[13];
  const int N = in_sizes[0] / 64;
  const int E = in_sizes[1] / 2;

  const int NB = (N + 511) >> 9;          // 512 rows per bucket
  const int NBpad = (NB + 63) & ~63;
  const int CH = (E + 255) / 256;

  float* ws = (float*)d_ws;
  long nAlign = (N + 255) & ~255L;
  float* dinv = ws;                                    // N
  int*   rowptr = (int*)(ws + nAlign);                 // N+1
  u16*   xb   = (u16*)(ws + 2 * nAlign + 256);         // N*64 bf16
  u16*   aggb = xb + (long)N * 64;                     // N*64 bf16
  u8*    xq   = (u8*)(aggb + (long)N * 64);            // N*64 fp8
  float* bp   = (float*)(xq + ((long)N * 64 + 255 & ~255L));  // 128
  u16*   W1xf = (u16*)(bp + 128);                      // 8192
  u16*   W1af = W1xf + 8192;                           // 8192
  u16*   Wxpf = W1af + 8192;                           // 16384
  u16*   Wapf = Wxpf + 16384;                          // 16384
  u16*   Wclsf = Wapf + 16384;                         // 8192
  int*   bh   = (int*)(Wclsf + 8192);                  // 256*NBpad
  int*   bstart = bh + 256 * NBpad;                    // NB+1 (+pad)
  u32*   staged = (u32*)(bstart + NB + 64);            // E
  u32*   cols   = staged + E;                          // E
  float* out = (float*)d_out;

  k_bhist_cvt<<<256, 256, 0, stream>>>(ei, E, CH, NB, NBpad, bh, x, xb, xq,
                                       (long)N * 64);
  k_cscan<<<1, 256, 0, stream>>>(bh, bstart, NB, NBpad, E);
  k_partition<<<256, 256, 0, stream>>>(ei, E, CH, NB, NBpad, bh, staged);
  k_csr_bucket<<<NB, 1024, 0, stream>>>(staged, bstart, rowptr, dinv, cols, N, E);
  k_aggregate<<<(N + 7) / 8, 256, 0, stream>>>(rowptr, cols, xb, xq, dinv, aggb, N);
  k_wpack<<<225, 256, 0, stream>>>(W1x, W1a, W2x, W2a, Wc, b2x, b2a, bc, Wcls,
                                   W1xf, W1af, Wxpf, Wapf, Wclsf, bp);
  k_mlp<<<(N + 63) / 64, 256, 0, stream>>>(xb, aggb, W1xf, W1af, b1x, b1a,
                                           Wxpf, Wapf, bp, Wclsf, bcls, out, N);
}

// Round 18
// 151.671 us; speedup vs baseline: 1.0937x; 1.0071x over previous
//
#include <hip/hip_runtime.h>
#include <stdint.h>

typedef unsigned short u16;
typedef unsigned char u8;
typedef unsigned int u32;
typedef __attribute__((ext_vector_type(8))) short frag_ab;   // 8 bf16
typedef __attribute__((ext_vector_type(4))) float f32x4;

__device__ __forceinline__ u16 f2b(float f) {
  unsigned u = __float_as_uint(f);
  return (u16)((u + 0x7fffu + ((u >> 16) & 1u)) >> 16);
}
__device__ __forceinline__ float b2f(u16 u) {
  return __uint_as_float(((unsigned)u) << 16);
}

// all-wave inline int64 detection: odd int32 slots of first 64 elems all zero
__device__ __forceinline__ int detect64(const int* __restrict__ ei32) {
  int v = ei32[2 * (threadIdx.x & 63) + 1];
  unsigned long long b = __ballot(v == 0);
  return (b == ~0ULL) ? 1 : 0;
}

__device__ __forceinline__ int edge_at(const void* ei, long pos, int is64) {
  if (is64) return (int)((const long long*)ei)[pos];
  return ((const int*)ei)[pos];
}

// ---------------------------------------------------------------------------
// per-(chunk,bucket) histogram (bucket = row>>9) + fused convert:
//   xb = bf16(x)  (MFMA path, self-loop)      xq = fp8 e4m3(x)  (gather path)
__global__ __launch_bounds__(256) void k_bhist_cvt(
    const void* __restrict__ ei, int E, int CH, int NB, int NBpad,
    int* __restrict__ bh,
    const float* __restrict__ x, u16* __restrict__ xb, u8* __restrict__ xq,
    long n64) {
  __shared__ int cnt[512];
  const int k = blockIdx.x, tid = threadIdx.x;
  const int is64 = detect64((const int*)ei);
  for (long i = ((long)k * 256 + tid) * 8; i < n64; i += 65536L * 8) {
    float4 v0 = *(const float4*)(x + i);
    float4 v1 = *(const float4*)(x + i + 4);
    frag_ab o;
    o[0] = (short)f2b(v0.x); o[1] = (short)f2b(v0.y);
    o[2] = (short)f2b(v0.z); o[3] = (short)f2b(v0.w);
    o[4] = (short)f2b(v1.x); o[5] = (short)f2b(v1.y);
    o[6] = (short)f2b(v1.z); o[7] = (short)f2b(v1.w);
    *(frag_ab*)(xb + i) = o;
    u32 p0 = (u32)__builtin_amdgcn_cvt_pk_fp8_f32(v0.x, v0.y, 0, false);
    p0 = (u32)__builtin_amdgcn_cvt_pk_fp8_f32(v0.z, v0.w, (int)p0, true);
    u32 p1 = (u32)__builtin_amdgcn_cvt_pk_fp8_f32(v1.x, v1.y, 0, false);
    p1 = (u32)__builtin_amdgcn_cvt_pk_fp8_f32(v1.z, v1.w, (int)p1, true);
    *(uint2*)(xq + i) = make_uint2(p0, p1);
  }
  for (int t = tid; t < NB; t += 256) cnt[t] = 0;
  __syncthreads();
  int e0 = k * CH, e1 = min(E, e0 + CH);
  for (int e = e0 + tid; e < e1; e += 256)
    atomicAdd(&cnt[edge_at(ei, e, is64) >> 9], 1);
  __syncthreads();
  for (int t = tid; t < NB; t += 256) bh[k * NBpad + t] = cnt[t];
}

// bucket starts + in-place column prefix: bh[k][b] -> absolute staged offset
__global__ __launch_bounds__(256) void k_cscan(
    int* __restrict__ bh, int* __restrict__ bstart, int NB, int NBpad, int E) {
  __shared__ int s[256];
  const int b = threadIdx.x;
  int tot = 0;
  if (b < NB)
    for (int k = 0; k < 256; ++k) tot += bh[k * NBpad + b];
  s[b] = (b < NB) ? tot : 0;
  __syncthreads();
  for (int off = 1; off < 256; off <<= 1) {
    int u = (b >= off) ? s[b - off] : 0;
    __syncthreads();
    s[b] += u;
    __syncthreads();
  }
  int excl = s[b] - tot;
  if (b < NB) {
    bstart[b] = excl;
    int run = excl;
    for (int k = 0; k < 256; ++k) {
      int t = bh[k * NBpad + b];
      bh[k * NBpad + b] = run;
      run += t;
    }
  }
  if (b == 0) bstart[NB] = E;
}

// append edges to this chunk's reserved per-bucket runs; pack (row&511)<<23|col
__global__ __launch_bounds__(256) void k_partition(
    const void* __restrict__ ei, int E, int CH, int NB, int NBpad,
    const int* __restrict__ bh, u32* __restrict__ staged) {
  __shared__ int cur[512];
  const int k = blockIdx.x, tid = threadIdx.x;
  const int is64 = detect64((const int*)ei);
  for (int t = tid; t < NB; t += 256) cur[t] = bh[k * NBpad + t];
  __syncthreads();
  int e0 = k * CH, e1 = min(E, e0 + CH);
  for (int e = e0 + tid; e < e1; e += 256) {
    int r = edge_at(ei, e, is64);
    int c = edge_at(ei, (long)E + e, is64);
    int pos = atomicAdd(&cur[r >> 9], 1);
    staged[pos] = ((u32)(r & 511) << 23) | (u32)c;
  }
}

// one block per bucket: local degree histogram -> rowptr/dinv, then scatter
__global__ __launch_bounds__(1024) void k_csr_bucket(
    const u32* __restrict__ staged, const int* __restrict__ bstart,
    int* __restrict__ rowptr, float* __restrict__ dinv,
    u32* __restrict__ cols, int N, int E) {
  __shared__ int cnt[512];
  __shared__ int cur[512];
  const int b = blockIdx.x, tid = threadIdx.x;
  const int r0 = b << 9;
  if (tid < 512) cnt[tid] = 0;
  __syncthreads();
  const int j0 = bstart[b], j1 = bstart[b + 1];
  for (int j = j0 + tid; j < j1; j += 1024)
    atomicAdd(&cnt[staged[j] >> 23], 1);
  __syncthreads();
  if (tid < 512) cur[tid] = cnt[tid];
  __syncthreads();
  for (int off = 1; off < 512; off <<= 1) {
    int v = 0;
    if (tid < 512 && tid >= off) v = cur[tid - off];
    __syncthreads();
    if (tid < 512) cur[tid] += v;
    __syncthreads();
  }
  int myStart = 0;
  if (tid < 512) {
    myStart = j0 + cur[tid] - cnt[tid];
    int r = r0 + tid;
    if (r < N) {
      rowptr[r] = myStart;
      dinv[r] = rsqrtf((float)cnt[tid] + 1.0f);  // +1 = self loop
    }
  }
  __syncthreads();
  if (tid < 512) cur[tid] = myStart;
  if (b == 0 && tid == 0) rowptr[N] = E;
  __syncthreads();
  for (int j = j0 + tid; j < j1; j += 1024) {
    u32 v = staged[j];
    int rl = v >> 23;
    int pos = atomicAdd(&cur[rl], 1);
    cols[pos] = v & 0x7FFFFF;
  }
}

// TWO rows per wave, plain loads (measured floor ~46us: miss-concurrency
// x L3-latency model gives 41us)
__global__ __launch_bounds__(256, 4) void k_aggregate(
    const int* __restrict__ rowptr, const u32* __restrict__ cols,
    const u16* __restrict__ xb, const u8* __restrict__ xq,
    const float* __restrict__ dinv, u16* __restrict__ aggb, int N) {
  int q = (blockIdx.x * 256 + threadIdx.x) >> 6;   // wave id
  int f = threadIdx.x & 63;
  int r0 = q * 2, r1 = q * 2 + 1;
  if (r0 >= N) return;
  const bool has1 = (r1 < N);
  int j0 = rowptr[r0], e0 = rowptr[r0 + 1];
  int j1 = has1 ? rowptr[r1] : 0;
  int e1 = has1 ? rowptr[r1 + 1] : 0;
  float d0 = dinv[r0];
  float d1 = has1 ? dinv[r1] : 0.f;
  float acc0 = b2f(xb[(long)r0 * 64 + f]) * d0;
  float acc1 = has1 ? b2f(xb[(long)r1 * 64 + f]) * d1 : 0.f;
  while (j0 + 8 <= e0 && j1 + 8 <= e1) {
    int ca[8], cb[8];
#pragma unroll
    for (int i = 0; i < 8; ++i) { ca[i] = cols[j0 + i]; cb[i] = cols[j1 + i]; }
    int qa[8], qb[8];
    float wa[8], wb[8];
#pragma unroll
    for (int i = 0; i < 8; ++i) {
      qa[i] = xq[(long)ca[i] * 64 + f];
      qb[i] = xq[(long)cb[i] * 64 + f];
      wa[i] = dinv[ca[i]];
      wb[i] = dinv[cb[i]];
    }
    __builtin_amdgcn_sched_barrier(0);
#pragma unroll
    for (int i = 0; i < 8; ++i) {
      acc0 = fmaf(__builtin_amdgcn_cvt_f32_fp8(qa[i], 0), wa[i], acc0);
      acc1 = fmaf(__builtin_amdgcn_cvt_f32_fp8(qb[i], 0), wb[i], acc1);
    }
    j0 += 8; j1 += 8;
  }
  while (j0 + 4 <= e0 && j1 + 4 <= e1) {
    int ca[4], cb[4];
#pragma unroll
    for (int i = 0; i < 4; ++i) { ca[i] = cols[j0 + i]; cb[i] = cols[j1 + i]; }
    int qa[4], qb[4];
    float wa[4], wb[4];
#pragma unroll
    for (int i = 0; i < 4; ++i) {
      qa[i] = xq[(long)ca[i] * 64 + f];
      qb[i] = xq[(long)cb[i] * 64 + f];
      wa[i] = dinv[ca[i]];
      wb[i] = dinv[cb[i]];
    }
    __builtin_amdgcn_sched_barrier(0);
#pragma unroll
    for (int i = 0; i < 4; ++i) {
      acc0 = fmaf(__builtin_amdgcn_cvt_f32_fp8(qa[i], 0), wa[i], acc0);
      acc1 = fmaf(__builtin_amdgcn_cvt_f32_fp8(qb[i], 0), wb[i], acc1);
    }
    j0 += 4; j1 += 4;
  }
  for (; j0 + 4 <= e0; j0 += 4) {
    int c0 = cols[j0], c1 = cols[j0 + 1], c2 = cols[j0 + 2], c3 = cols[j0 + 3];
    int q0 = xq[(long)c0 * 64 + f];
    int q1 = xq[(long)c1 * 64 + f];
    int q2 = xq[(long)c2 * 64 + f];
    int q3 = xq[(long)c3 * 64 + f];
    acc0 = fmaf(__builtin_amdgcn_cvt_f32_fp8(q0, 0), dinv[c0], acc0);
    acc0 = fmaf(__builtin_amdgcn_cvt_f32_fp8(q1, 0), dinv[c1], acc0);
    acc0 = fmaf(__builtin_amdgcn_cvt_f32_fp8(q2, 0), dinv[c2], acc0);
    acc0 = fmaf(__builtin_amdgcn_cvt_f32_fp8(q3, 0), dinv[c3], acc0);
  }
  for (; j0 < e0; ++j0) {
    int c = cols[j0];
    acc0 = fmaf(__builtin_amdgcn_cvt_f32_fp8((int)xq[(long)c * 64 + f], 0),
                dinv[c], acc0);
  }
  for (; j1 + 4 <= e1; j1 += 4) {
    int c0 = cols[j1], c1 = cols[j1 + 1], c2 = cols[j1 + 2], c3 = cols[j1 + 3];
    int q0 = xq[(long)c0 * 64 + f];
    int q1 = xq[(long)c1 * 64 + f];
    int q2 = xq[(long)c2 * 64 + f];
    int q3 = xq[(long)c3 * 64 + f];
    acc1 = fmaf(__builtin_amdgcn_cvt_f32_fp8(q0, 0), dinv[c0], acc1);
    acc1 = fmaf(__builtin_amdgcn_cvt_f32_fp8(q1, 0), dinv[c1], acc1);
    acc1 = fmaf(__builtin_amdgcn_cvt_f32_fp8(q2, 0), dinv[c2], acc1);
    acc1 = fmaf(__builtin_amdgcn_cvt_f32_fp8(q3, 0), dinv[c3], acc1);
  }
  for (; j1 < e1; ++j1) {
    int c = cols[j1];
    acc1 = fmaf(__builtin_amdgcn_cvt_f32_fp8((int)xq[(long)c * 64 + f], 0),
                dinv[c], acc1);
  }
  aggb[(long)r0 * 64 + f] = f2b(acc0 * d0);
  if (has1) aggb[(long)r1 * 64 + f] = f2b(acc1 * d1);
}

// ---------------------------------------------------------------------------
// One-shot weight prep (unchanged)
// ---------------------------------------------------------------------------
__global__ __launch_bounds__(256) void k_wpack(
    const float* __restrict__ W1x, const float* __restrict__ W1a,
    const float* __restrict__ W2x, const float* __restrict__ W2a,
    const float* __restrict__ Wc, const float* __restrict__ b2x,
    const float* __restrict__ b2a, const float* __restrict__ bc,
    const float* __restrict__ Wcls,
    u16* __restrict__ W1xf, u16* __restrict__ W1af,
    u16* __restrict__ Wxpf, u16* __restrict__ Wapf,
    u16* __restrict__ Wclsf, float* __restrict__ bp) {
  const int blk = blockIdx.x, t = threadIdx.x;
  if (blk < 128) {
    const bool isX = blk < 64;
    int i = (isX ? blk : blk - 64) * 256 + t;        // packed index, K=128 Nc=128
    const float* W2 = isX ? W2x : W2a;
    const float* wc = isX ? Wc : Wc + 128 * 128;
    int b = i & 7, l = (i >> 3) & 63, fi = i >> 9;
    int kb = fi & 3, nb = fi >> 2;                   // KB = 4
    int k = kb * 32 + (l >> 4) * 8 + b;
    int n = nb * 16 + (l & 15);
    float s = 0.f;
    for (int m = 0; m < 128; ++m) s = fmaf(W2[k * 128 + m], wc[m * 128 + n], s);
    (isX ? Wxpf : Wapf)[i] = f2b(s);
  } else if (blk < 224) {
    const float* W; u16* dst; int K, Nc, i0;
    if (blk < 160)      { W = W1x;  dst = W1xf;  K = 64;  Nc = 128; i0 = blk - 128; }
    else if (blk < 192) { W = W1a;  dst = W1af;  K = 64;  Nc = 128; i0 = blk - 160; }
    else                { W = Wcls; dst = Wclsf; K = 128; Nc = 64;  i0 = blk - 192; }
    int i = i0 * 256 + t;
    if (i < K * Nc) {
      int b = i & 7, l = (i >> 3) & 63, fi = i >> 9;
      int KB = K >> 5;
      int kb = fi % KB, nb = fi / KB;
      int k = kb * 32 + (l >> 4) * 8 + b;
      int n = nb * 16 + (l & 15);
      dst[i] = f2b(W[k * Nc + n]);
    }
  } else if (t < 128) {
    float s = bc[t];
    for (int m = 0; m < 128; ++m)
      s += b2x[m] * Wc[m * 128 + t] + b2a[m] * Wc[(128 + m) * 128 + t];
    bp[t] = s;
  }
}

// ---------------------------------------------------------------------------
// Fused MLP v8: LDS-STAGED WEIGHTS (canonical §5 pattern, finally applied).
// 4-wave row-split blocks. 32KB H-slices + 32KB weight stage = 64KB/block.
// Weights copied global->LDS once per block (cooperative, coalesced);
// B-frags consumed via ds_read_b128 (128B/clk LDS port, no L2 latency).
// Phase 2 split into Wxp half + Wap half with persistent accumulators.
// ---------------------------------------------------------------------------
__global__ __launch_bounds__(256, 2) void k_mlp(
    const u16* __restrict__ xb, const u16* __restrict__ aggb,
    const u16* __restrict__ W1xf, const u16* __restrict__ W1af,
    const float* __restrict__ b1x, const float* __restrict__ b1a,
    const u16* __restrict__ Wxpf, const u16* __restrict__ Wapf,
    const float* __restrict__ bp,
    const u16* __restrict__ Wclsf, const float* __restrict__ bcls,
    float* __restrict__ out, int N) {
  __shared__ u16 S[4][16 * 256];    // 32KB H slices (per-wave 8KB)
  __shared__ u16 WS[16384];         // 32KB weight stage, reused per chunk
  const int tid = threadIdx.x;
  const int w = tid >> 6;
  const int lane = tid & 63;
  const int m0 = blockIdx.x * 64 + w * 16;
  const int lm = lane & 15;
  const int lq = lane >> 4;
  u16* s = S[w];

  // ---- stage chunk A: W1xf (16KB) + W1af (16KB)
  {
    const uint4* s1 = (const uint4*)W1xf;
    const uint4* s2 = (const uint4*)W1af;
    uint4* d = (uint4*)WS;
#pragma unroll
    for (int i = 0; i < 4; ++i) d[tid + i * 256] = s1[tid + i * 256];
#pragma unroll
    for (int i = 0; i < 4; ++i) d[1024 + tid + i * 256] = s2[tid + i * 256];
  }
  __syncthreads();

  // ---- phase 1: s[row*256+col] = relu([x|agg]@W1+b1), swizzled
  for (int br = 0; br < 2; ++br) {
    const u16* A = br ? aggb : xb;
    const u16* Wl = WS + (br ? 8192 : 0);
    const float* bias = br ? b1a : b1x;
    const u16* ap = A + (long)(m0 + lm) * 64 + lq * 8;
    frag_ab a0 = *(const frag_ab*)(ap);
    frag_ab a1 = *(const frag_ab*)(ap + 32);
#pragma unroll
    for (int nb = 0; nb < 8; ++nb) {
      frag_ab b0 = *(const frag_ab*)(Wl + (size_t)((nb * 2 + 0) * 64 + lane) * 8);
      frag_ab b1v = *(const frag_ab*)(Wl + (size_t)((nb * 2 + 1) * 64 + lane) * 8);
      f32x4 acc = {0.f, 0.f, 0.f, 0.f};
      acc = __builtin_amdgcn_mfma_f32_16x16x32_bf16(a0, b0, acc, 0, 0, 0);
      acc = __builtin_amdgcn_mfma_f32_16x16x32_bf16(a1, b1v, acc, 0, 0, 0);
      int col = nb * 16 + lm;
      float bv = bias[col];
#pragma unroll
      for (int r = 0; r < 4; ++r) {
        int row = lq * 4 + r;
        s[(row * 256 + br * 128 + col) ^ ((row & 7) << 3)] =
            f2b(fmaxf(acc[r] + bv, 0.f));
      }
    }
  }

  // ---- read full H1 fragment set into regs (own slice, per-wave in-order)
  frag_ab hfr[8];
#pragma unroll
  for (int kb = 0; kb < 8; ++kb)
    hfr[kb] = *(const frag_ab*)&s[(lm * 256 + kb * 32 + lq * 8) ^ ((lm & 7) << 3)];
  __syncthreads();   // everyone done with chunk A + H1 reads

  // ---- stage chunk B1: Wxpf (32KB)
  {
    const uint4* s1 = (const uint4*)Wxpf;
    uint4* d = (uint4*)WS;
#pragma unroll
    for (int i = 0; i < 8; ++i) d[tid + i * 256] = s1[tid + i * 256];
  }
  __syncthreads();
  f32x4 accs[8];
#pragma unroll
  for (int nb = 0; nb < 8; ++nb) accs[nb] = (f32x4){0.f, 0.f, 0.f, 0.f};
#pragma unroll
  for (int nb = 0; nb < 8; ++nb)
#pragma unroll
    for (int kb = 0; kb < 4; ++kb) {
      frag_ab b = *(const frag_ab*)(WS + (size_t)((nb * 4 + kb) * 64 + lane) * 8);
      accs[nb] = __builtin_amdgcn_mfma_f32_16x16x32_bf16(hfr[kb], b, accs[nb], 0, 0, 0);
    }
  __syncthreads();

  // ---- stage chunk B2: Wapf (32KB)
  {
    const uint4* s1 = (const uint4*)Wapf;
    uint4* d = (uint4*)WS;
#pragma unroll
    for (int i = 0; i < 8; ++i) d[tid + i * 256] = s1[tid + i * 256];
  }
  __syncthreads();
#pragma unroll
  for (int nb = 0; nb < 8; ++nb) {
#pragma unroll
    for (int kb = 0; kb < 4; ++kb) {
      frag_ab b = *(const frag_ab*)(WS + (size_t)((nb * 4 + kb) * 64 + lane) * 8);
      accs[nb] = __builtin_amdgcn_mfma_f32_16x16x32_bf16(hfr[4 + kb], b, accs[nb], 0, 0, 0);
    }
    int col = nb * 16 + lm;
    float bv = bp[col];
#pragma unroll
    for (int r = 0; r < 4; ++r) {
      int row = lq * 4 + r;
      s[(row * 128 + col) ^ ((row & 7) << 3)] = f2b(fmaxf(accs[nb][r] + bv, 0.f));
    }
  }

  // ---- read H2 frags (own slice), then stage chunk C: Wclsf (16KB)
  frag_ab h3[4];
#pragma unroll
  for (int kb = 0; kb < 4; ++kb)
    h3[kb] = *(const frag_ab*)&s[(lm * 128 + kb * 32 + lq * 8) ^ ((lm & 7) << 3)];
  __syncthreads();
  {
    const uint4* s1 = (const uint4*)Wclsf;
    uint4* d = (uint4*)WS;
#pragma unroll
    for (int i = 0; i < 4; ++i) d[tid + i * 256] = s1[tid + i * 256];
  }
  __syncthreads();
#pragma unroll
  for (int nb = 0; nb < 4; ++nb) {
    f32x4 acc = {0.f, 0.f, 0.f, 0.f};
#pragma unroll
    for (int kb = 0; kb < 4; ++kb) {
      frag_ab b = *(const frag_ab*)(WS + (size_t)((nb * 4 + kb) * 64 + lane) * 8);
      acc = __builtin_amdgcn_mfma_f32_16x16x32_bf16(h3[kb], b, acc, 0, 0, 0);
    }
    int col = nb * 16 + lm;
    float bv = bcls[col];
#pragma unroll
    for (int r = 0; r < 4; ++r) {
      int grow = m0 + lq * 4 + r;
      if (grow < N) out[(long)grow * 64 + col] = acc[r] + bv;
    }
  }
}

extern "C" void kernel_launch(void* const* d_in, const int* in_sizes, int n_in,
                              void* d_out, int out_size, void* d_ws, size_t ws_size,
                              hipStream_t stream) {
  const float* x    = (const float*)d_in[0];
  const void*  ei   = d_in[1];
  const float* W1x  = (const float*)d_in[2];
  const float* b1x  = (const float*)d_in[3];
  const float* W2x  = (const float*)d_in[4];
  const float* b2x  = (const float*)d_in[5];
  const float* W1a  = (const float*)d_in[6];
  const float* b1a  = (const float*)d_in[7];
  const float* W2a  = (const float*)d_in[8];
  const float* b2a  = (const float*)d_in[9];
  const float* Wc   = (const float*)d_in[10];
  const float* bc   = (const float*)d_in[11];
  const float* Wcls = (const float*)d_in[12];
  const float* bcls = (const float*)d_in[13];
  const int N = in_sizes[0] / 64;
  const int E = in_sizes[1] / 2;

  const int NB = (N + 511) >> 9;          // 512 rows per bucket
  const int NBpad = (NB + 63) & ~63;
  const int CH = (E + 255) / 256;

  float* ws = (float*)d_ws;
  long nAlign = (N + 255) & ~255L;
  float* dinv = ws;                                    // N
  int*   rowptr = (int*)(ws + nAlign);                 // N+1
  u16*   xb   = (u16*)(ws + 2 * nAlign + 256);         // N*64 bf16
  u16*   aggb = xb + (long)N * 64;                     // N*64 bf16
  u8*    xq   = (u8*)(aggb + (long)N * 64);            // N*64 fp8
  float* bp   = (float*)(xq + ((long)N * 64 + 255 & ~255L));  // 128
  u16*   W1xf = (u16*)(bp + 128);                      // 8192
  u16*   W1af = W1xf + 8192;                           // 8192
  u16*   Wxpf = W1af + 8192;                           // 16384
  u16*   Wapf = Wxpf + 16384;                          // 16384
  u16*   Wclsf = Wapf + 16384;                         // 8192
  int*   bh   = (int*)(Wclsf + 8192);                  // 256*NBpad
  int*   bstart = bh + 256 * NBpad;                    // NB+1 (+pad)
  u32*   staged = (u32*)(bstart + NB + 64);            // E
  u32*   cols   = staged + E;                          // E
  float* out = (float*)d_out;

  k_bhist_cvt<<<256, 256, 0, stream>>>(ei, E, CH, NB, NBpad, bh, x, xb, xq,
                                       (long)N * 64);
  k_cscan<<<1, 256, 0, stream>>>(bh, bstart, NB, NBpad, E);
  k_partition<<<256, 256, 0, stream>>>(ei, E, CH, NB, NBpad, bh, staged);
  k_csr_bucket<<<NB, 1024, 0, stream>>>(staged, bstart, rowptr, dinv, cols, N, E);
  k_aggregate<<<(N + 7) / 8, 256, 0, stream>>>(rowptr, cols, xb, xq, dinv, aggb, N);
  k_wpack<<<225, 256, 0, stream>>>(W1x, W1a, W2x, W2a, Wc, b2x, b2a, bc, Wcls,
                                   W1xf, W1af, Wxpf, Wapf, Wclsf, bp);
  k_mlp<<<(N + 63) / 64, 256, 0, stream>>>(xb, aggb, W1xf, W1af, b1x, b1a,
                                           Wxpf, Wapf, bp, Wclsf, bcls, out, N);
}

// Round 19
// 149.136 us; speedup vs baseline: 1.1123x; 1.0170x over previous
//
#include <hip/hip_runtime.h>
#include <stdint.h>

typedef unsigned short u16;
typedef unsigned char u8;
typedef unsigned int u32;
typedef __attribute__((ext_vector_type(8))) short frag_ab;   // 8 bf16
typedef __attribute__((ext_vector_type(4))) float f32x4;

__device__ __forceinline__ u16 f2b(float f) {
  unsigned u = __float_as_uint(f);
  return (u16)((u + 0x7fffu + ((u >> 16) & 1u)) >> 16);
}
__device__ __forceinline__ float b2f(u16 u) {
  return __uint_as_float(((unsigned)u) << 16);
}

// all-wave inline int64 detection: odd int32 slots of first 64 elems all zero
__device__ __forceinline__ int detect64(const int* __restrict__ ei32) {
  int v = ei32[2 * (threadIdx.x & 63) + 1];
  unsigned long long b = __ballot(v == 0);
  return (b == ~0ULL) ? 1 : 0;
}

__device__ __forceinline__ int edge_at(const void* ei, long pos, int is64) {
  if (is64) return (int)((const long long*)ei)[pos];
  return ((const int*)ei)[pos];
}

// ---------------------------------------------------------------------------
// per-(chunk,bucket) histogram (bucket = row>>9) + fused convert:
//   xb = bf16(x)  (MFMA path, self-loop)      xq = fp8 e4m3(x)  (gather path)
__global__ __launch_bounds__(256) void k_bhist_cvt(
    const void* __restrict__ ei, int E, int CH, int NB, int NBpad,
    int* __restrict__ bh,
    const float* __restrict__ x, u16* __restrict__ xb, u8* __restrict__ xq,
    long n64) {
  __shared__ int cnt[512];
  const int k = blockIdx.x, tid = threadIdx.x;
  const int is64 = detect64((const int*)ei);
  for (long i = ((long)k * 256 + tid) * 8; i < n64; i += 65536L * 8) {
    float4 v0 = *(const float4*)(x + i);
    float4 v1 = *(const float4*)(x + i + 4);
    frag_ab o;
    o[0] = (short)f2b(v0.x); o[1] = (short)f2b(v0.y);
    o[2] = (short)f2b(v0.z); o[3] = (short)f2b(v0.w);
    o[4] = (short)f2b(v1.x); o[5] = (short)f2b(v1.y);
    o[6] = (short)f2b(v1.z); o[7] = (short)f2b(v1.w);
    *(frag_ab*)(xb + i) = o;
    u32 p0 = (u32)__builtin_amdgcn_cvt_pk_fp8_f32(v0.x, v0.y, 0, false);
    p0 = (u32)__builtin_amdgcn_cvt_pk_fp8_f32(v0.z, v0.w, (int)p0, true);
    u32 p1 = (u32)__builtin_amdgcn_cvt_pk_fp8_f32(v1.x, v1.y, 0, false);
    p1 = (u32)__builtin_amdgcn_cvt_pk_fp8_f32(v1.z, v1.w, (int)p1, true);
    *(uint2*)(xq + i) = make_uint2(p0, p1);
  }
  for (int t = tid; t < NB; t += 256) cnt[t] = 0;
  __syncthreads();
  int e0 = k * CH, e1 = min(E, e0 + CH);
  for (int e = e0 + tid; e < e1; e += 256)
    atomicAdd(&cnt[edge_at(ei, e, is64) >> 9], 1);
  __syncthreads();
  for (int t = tid; t < NB; t += 256) bh[k * NBpad + t] = cnt[t];
}

// bucket starts + in-place column prefix: bh[k][b] -> absolute staged offset
__global__ __launch_bounds__(256) void k_cscan(
    int* __restrict__ bh, int* __restrict__ bstart, int NB, int NBpad, int E) {
  __shared__ int s[256];
  const int b = threadIdx.x;
  int tot = 0;
  if (b < NB)
    for (int k = 0; k < 256; ++k) tot += bh[k * NBpad + b];
  s[b] = (b < NB) ? tot : 0;
  __syncthreads();
  for (int off = 1; off < 256; off <<= 1) {
    int u = (b >= off) ? s[b - off] : 0;
    __syncthreads();
    s[b] += u;
    __syncthreads();
  }
  int excl = s[b] - tot;
  if (b < NB) {
    bstart[b] = excl;
    int run = excl;
    for (int k = 0; k < 256; ++k) {
      int t = bh[k * NBpad + b];
      bh[k * NBpad + b] = run;
      run += t;
    }
  }
  if (b == 0) bstart[NB] = E;
}

// append edges to this chunk's reserved per-bucket runs; pack (row&511)<<23|col
__global__ __launch_bounds__(256) void k_partition(
    const void* __restrict__ ei, int E, int CH, int NB, int NBpad,
    const int* __restrict__ bh, u32* __restrict__ staged) {
  __shared__ int cur[512];
  const int k = blockIdx.x, tid = threadIdx.x;
  const int is64 = detect64((const int*)ei);
  for (int t = tid; t < NB; t += 256) cur[t] = bh[k * NBpad + t];
  __syncthreads();
  int e0 = k * CH, e1 = min(E, e0 + CH);
  for (int e = e0 + tid; e < e1; e += 256) {
    int r = edge_at(ei, e, is64);
    int c = edge_at(ei, (long)E + e, is64);
    int pos = atomicAdd(&cur[r >> 9], 1);
    staged[pos] = ((u32)(r & 511) << 23) | (u32)c;
  }
}

// one block per bucket: local degree histogram -> rowptr/dinv, then scatter
__global__ __launch_bounds__(1024) void k_csr_bucket(
    const u32* __restrict__ staged, const int* __restrict__ bstart,
    int* __restrict__ rowptr, float* __restrict__ dinv,
    u32* __restrict__ cols, int N, int E) {
  __shared__ int cnt[512];
  __shared__ int cur[512];
  const int b = blockIdx.x, tid = threadIdx.x;
  const int r0 = b << 9;
  if (tid < 512) cnt[tid] = 0;
  __syncthreads();
  const int j0 = bstart[b], j1 = bstart[b + 1];
  for (int j = j0 + tid; j < j1; j += 1024)
    atomicAdd(&cnt[staged[j] >> 23], 1);
  __syncthreads();
  if (tid < 512) cur[tid] = cnt[tid];
  __syncthreads();
  for (int off = 1; off < 512; off <<= 1) {
    int v = 0;
    if (tid < 512 && tid >= off) v = cur[tid - off];
    __syncthreads();
    if (tid < 512) cur[tid] += v;
    __syncthreads();
  }
  int myStart = 0;
  if (tid < 512) {
    myStart = j0 + cur[tid] - cnt[tid];
    int r = r0 + tid;
    if (r < N) {
      rowptr[r] = myStart;
      dinv[r] = rsqrtf((float)cnt[tid] + 1.0f);  // +1 = self loop
    }
  }
  __syncthreads();
  if (tid < 512) cur[tid] = myStart;
  if (b == 0 && tid == 0) rowptr[N] = E;
  __syncthreads();
  for (int j = j0 + tid; j < j1; j += 1024) {
    u32 v = staged[j];
    int rl = v >> 23;
    int pos = atomicAdd(&cur[rl], 1);
    cols[pos] = v & 0x7FFFFF;
  }
}

// TWO rows per wave, plain loads (measured floor ~46us)
__global__ __launch_bounds__(256, 4) void k_aggregate(
    const int* __restrict__ rowptr, const u32* __restrict__ cols,
    const u16* __restrict__ xb, const u8* __restrict__ xq,
    const float* __restrict__ dinv, u16* __restrict__ aggb, int N) {
  int q = (blockIdx.x * 256 + threadIdx.x) >> 6;   // wave id
  int f = threadIdx.x & 63;
  int r0 = q * 2, r1 = q * 2 + 1;
  if (r0 >= N) return;
  const bool has1 = (r1 < N);
  int j0 = rowptr[r0], e0 = rowptr[r0 + 1];
  int j1 = has1 ? rowptr[r1] : 0;
  int e1 = has1 ? rowptr[r1 + 1] : 0;
  float d0 = dinv[r0];
  float d1 = has1 ? dinv[r1] : 0.f;
  float acc0 = b2f(xb[(long)r0 * 64 + f]) * d0;
  float acc1 = has1 ? b2f(xb[(long)r1 * 64 + f]) * d1 : 0.f;
  while (j0 + 8 <= e0 && j1 + 8 <= e1) {
    int ca[8], cb[8];
#pragma unroll
    for (int i = 0; i < 8; ++i) { ca[i] = cols[j0 + i]; cb[i] = cols[j1 + i]; }
    int qa[8], qb[8];
    float wa[8], wb[8];
#pragma unroll
    for (int i = 0; i < 8; ++i) {
      qa[i] = xq[(long)ca[i] * 64 + f];
      qb[i] = xq[(long)cb[i] * 64 + f];
      wa[i] = dinv[ca[i]];
      wb[i] = dinv[cb[i]];
    }
    __builtin_amdgcn_sched_barrier(0);
#pragma unroll
    for (int i = 0; i < 8; ++i) {
      acc0 = fmaf(__builtin_amdgcn_cvt_f32_fp8(qa[i], 0), wa[i], acc0);
      acc1 = fmaf(__builtin_amdgcn_cvt_f32_fp8(qb[i], 0), wb[i], acc1);
    }
    j0 += 8; j1 += 8;
  }
  while (j0 + 4 <= e0 && j1 + 4 <= e1) {
    int ca[4], cb[4];
#pragma unroll
    for (int i = 0; i < 4; ++i) { ca[i] = cols[j0 + i]; cb[i] = cols[j1 + i]; }
    int qa[4], qb[4];
    float wa[4], wb[4];
#pragma unroll
    for (int i = 0; i < 4; ++i) {
      qa[i] = xq[(long)ca[i] * 64 + f];
      qb[i] = xq[(long)cb[i] * 64 + f];
      wa[i] = dinv[ca[i]];
      wb[i] = dinv[cb[i]];
    }
    __builtin_amdgcn_sched_barrier(0);
#pragma unroll
    for (int i = 0; i < 4; ++i) {
      acc0 = fmaf(__builtin_amdgcn_cvt_f32_fp8(qa[i], 0), wa[i], acc0);
      acc1 = fmaf(__builtin_amdgcn_cvt_f32_fp8(qb[i], 0), wb[i], acc1);
    }
    j0 += 4; j1 += 4;
  }
  for (; j0 + 4 <= e0; j0 += 4) {
    int c0 = cols[j0], c1 = cols[j0 + 1], c2 = cols[j0 + 2], c3 = cols[j0 + 3];
    int q0 = xq[(long)c0 * 64 + f];
    int q1 = xq[(long)c1 * 64 + f];
    int q2 = xq[(long)c2 * 64 + f];
    int q3 = xq[(long)c3 * 64 + f];
    acc0 = fmaf(__builtin_amdgcn_cvt_f32_fp8(q0, 0), dinv[c0], acc0);
    acc0 = fmaf(__builtin_amdgcn_cvt_f32_fp8(q1, 0), dinv[c1], acc0);
    acc0 = fmaf(__builtin_amdgcn_cvt_f32_fp8(q2, 0), dinv[c2], acc0);
    acc0 = fmaf(__builtin_amdgcn_cvt_f32_fp8(q3, 0), dinv[c3], acc0);
  }
  for (; j0 < e0; ++j0) {
    int c = cols[j0];
    acc0 = fmaf(__builtin_amdgcn_cvt_f32_fp8((int)xq[(long)c * 64 + f], 0),
                dinv[c], acc0);
  }
  for (; j1 + 4 <= e1; j1 += 4) {
    int c0 = cols[j1], c1 = cols[j1 + 1], c2 = cols[j1 + 2], c3 = cols[j1 + 3];
    int q0 = xq[(long)c0 * 64 + f];
    int q1 = xq[(long)c1 * 64 + f];
    int q2 = xq[(long)c2 * 64 + f];
    int q3 = xq[(long)c3 * 64 + f];
    acc1 = fmaf(__builtin_amdgcn_cvt_f32_fp8(q0, 0), dinv[c0], acc1);
    acc1 = fmaf(__builtin_amdgcn_cvt_f32_fp8(q1, 0), dinv[c1], acc1);
    acc1 = fmaf(__builtin_amdgcn_cvt_f32_fp8(q2, 0), dinv[c2], acc1);
    acc1 = fmaf(__builtin_amdgcn_cvt_f32_fp8(q3, 0), dinv[c3], acc1);
  }
  for (; j1 < e1; ++j1) {
    int c = cols[j1];
    acc1 = fmaf(__builtin_amdgcn_cvt_f32_fp8((int)xq[(long)c * 64 + f], 0),
                dinv[c], acc1);
  }
  aggb[(long)r0 * 64 + f] = f2b(acc0 * d0);
  if (has1) aggb[(long)r1 * 64 + f] = f2b(acc1 * d1);
}

// ---------------------------------------------------------------------------
// One-shot weight prep (unchanged)
// ---------------------------------------------------------------------------
__global__ __launch_bounds__(256) void k_wpack(
    const float* __restrict__ W1x, const float* __restrict__ W1a,
    const float* __restrict__ W2x, const float* __restrict__ W2a,
    const float* __restrict__ Wc, const float* __restrict__ b2x,
    const float* __restrict__ b2a, const float* __restrict__ bc,
    const float* __restrict__ Wcls,
    u16* __restrict__ W1xf, u16* __restrict__ W1af,
    u16* __restrict__ Wxpf, u16* __restrict__ Wapf,
    u16* __restrict__ Wclsf, float* __restrict__ bp) {
  const int blk = blockIdx.x, t = threadIdx.x;
  if (blk < 128) {
    const bool isX = blk < 64;
    int i = (isX ? blk : blk - 64) * 256 + t;        // packed index, K=128 Nc=128
    const float* W2 = isX ? W2x : W2a;
    const float* wc = isX ? Wc : Wc + 128 * 128;
    int b = i & 7, l = (i >> 3) & 63, fi = i >> 9;
    int kb = fi & 3, nb = fi >> 2;                   // KB = 4
    int k = kb * 32 + (l >> 4) * 8 + b;
    int n = nb * 16 + (l & 15);
    float s = 0.f;
    for (int m = 0; m < 128; ++m) s = fmaf(W2[k * 128 + m], wc[m * 128 + n], s);
    (isX ? Wxpf : Wapf)[i] = f2b(s);
  } else if (blk < 224) {
    const float* W; u16* dst; int K, Nc, i0;
    if (blk < 160)      { W = W1x;  dst = W1xf;  K = 64;  Nc = 128; i0 = blk - 128; }
    else if (blk < 192) { W = W1a;  dst = W1af;  K = 64;  Nc = 128; i0 = blk - 160; }
    else                { W = Wcls; dst = Wclsf; K = 128; Nc = 64;  i0 = blk - 192; }
    int i = i0 * 256 + t;
    if (i < K * Nc) {
      int b = i & 7, l = (i >> 3) & 63, fi = i >> 9;
      int KB = K >> 5;
      int kb = fi % KB, nb = fi / KB;
      int k = kb * 32 + (l >> 4) * 8 + b;
      int n = nb * 16 + (l & 15);
      dst[i] = f2b(W[k * Nc + n]);
    }
  } else if (t < 128) {
    float s = bc[t];
    for (int m = 0; m < 128; ++m)
      s += b2x[m] * Wc[m * 128 + t] + b2a[m] * Wc[(128 + m) * 128 + t];
    bp[t] = s;
  }
}

// ---------------------------------------------------------------------------
// Fused MLP v9: 32 ROWS PER WAVE (two 16-row tiles; B-frags reused across
// tiles). Halves the machine-wide wave count 6252 -> 3126 — tests the
// "time ∝ wave count" model (R8: 4x work/wave at same wave count = same
// time). 4 waves x 32 rows = 128 rows/block, grid 782. LDS 16KB/wave
// (H2 unioned into H1 head), barrier-free wave-private slices.
// ---------------------------------------------------------------------------
__global__ __launch_bounds__(256, 2) void k_mlp(
    const u16* __restrict__ xb, const u16* __restrict__ aggb,
    const u16* __restrict__ W1xf, const u16* __restrict__ W1af,
    const float* __restrict__ b1x, const float* __restrict__ b1a,
    const u16* __restrict__ Wxpf, const u16* __restrict__ Wapf,
    const float* __restrict__ bp,
    const u16* __restrict__ Wclsf, const float* __restrict__ bcls,
    float* __restrict__ out, int N) {
  __shared__ u16 S[4][32 * 256];    // 64KB total; per-wave 16KB slice
  const int w = threadIdx.x >> 6;
  const int lane = threadIdx.x & 63;
  const int m0 = blockIdx.x * 128 + w * 32;
  const int lm = lane & 15;
  const int lq = lane >> 4;
  u16* s = S[w];

  // ---- phase 1: s[row*256+col] = relu([x|agg]@W1+b1), swizzled; 2 tiles
  for (int br = 0; br < 2; ++br) {
    const u16* A = br ? aggb : xb;
    const u16* Wf = br ? W1af : W1xf;
    const float* bias = br ? b1a : b1x;
    frag_ab a[2][2];
#pragma unroll
    for (int rt = 0; rt < 2; ++rt) {
      const u16* ap = A + (long)(m0 + rt * 16 + lm) * 64 + lq * 8;
      a[rt][0] = *(const frag_ab*)(ap);
      a[rt][1] = *(const frag_ab*)(ap + 32);
    }
#pragma unroll
    for (int nb = 0; nb < 8; ++nb) {
      frag_ab b0 = *(const frag_ab*)(Wf + (size_t)((nb * 2 + 0) * 64 + lane) * 8);
      frag_ab b1v = *(const frag_ab*)(Wf + (size_t)((nb * 2 + 1) * 64 + lane) * 8);
      int col = nb * 16 + lm;
      float bv = bias[col];
#pragma unroll
      for (int rt = 0; rt < 2; ++rt) {
        f32x4 acc = {0.f, 0.f, 0.f, 0.f};
        acc = __builtin_amdgcn_mfma_f32_16x16x32_bf16(a[rt][0], b0, acc, 0, 0, 0);
        acc = __builtin_amdgcn_mfma_f32_16x16x32_bf16(a[rt][1], b1v, acc, 0, 0, 0);
#pragma unroll
        for (int r = 0; r < 4; ++r) {
          int row = rt * 16 + lq * 4 + r;
          s[(row * 256 + br * 128 + col) ^ ((row & 7) << 3)] =
              f2b(fmaxf(acc[r] + bv, 0.f));
        }
      }
    }
  }
  __builtin_amdgcn_wave_barrier();

  // ---- phase 2: read full H1 fragment sets (both tiles) into regs, then
  // H2 overwrites the slice head (per-wave DS queue is in-order).
  frag_ab hfr[2][8];
#pragma unroll
  for (int rt = 0; rt < 2; ++rt)
#pragma unroll
    for (int kb = 0; kb < 8; ++kb) {
      int row = rt * 16 + lm;
      hfr[rt][kb] =
          *(const frag_ab*)&s[(row * 256 + kb * 32 + lq * 8) ^ ((lm & 7) << 3)];
    }
  __builtin_amdgcn_wave_barrier();
#pragma unroll
  for (int nb = 0; nb < 8; ++nb) {
    f32x4 acc[2] = {{0.f, 0.f, 0.f, 0.f}, {0.f, 0.f, 0.f, 0.f}};
#pragma unroll
    for (int kb = 0; kb < 8; ++kb) {
      const u16* Wf2 = (kb < 4) ? Wxpf : Wapf;
      frag_ab b = *(const frag_ab*)(Wf2 + (size_t)((nb * 4 + (kb & 3)) * 64 + lane) * 8);
#pragma unroll
      for (int rt = 0; rt < 2; ++rt)
        acc[rt] = __builtin_amdgcn_mfma_f32_16x16x32_bf16(hfr[rt][kb], b, acc[rt], 0, 0, 0);
    }
    int col = nb * 16 + lm;
    float bv = bp[col];
#pragma unroll
    for (int rt = 0; rt < 2; ++rt)
#pragma unroll
      for (int r = 0; r < 4; ++r) {
        int row = rt * 16 + lq * 4 + r;
        s[(row * 128 + col) ^ ((row & 7) << 3)] = f2b(fmaxf(acc[rt][r] + bv, 0.f));
      }
  }
  __builtin_amdgcn_wave_barrier();

  // ---- phase 3: out = H2 @ Wcls + bcls, K=128, both tiles
  frag_ab h3[2][4];
#pragma unroll
  for (int rt = 0; rt < 2; ++rt)
#pragma unroll
    for (int kb = 0; kb < 4; ++kb) {
      int row = rt * 16 + lm;
      h3[rt][kb] =
          *(const frag_ab*)&s[(row * 128 + kb * 32 + lq * 8) ^ ((lm & 7) << 3)];
    }
#pragma unroll
  for (int nb = 0; nb < 4; ++nb) {
    f32x4 acc[2] = {{0.f, 0.f, 0.f, 0.f}, {0.f, 0.f, 0.f, 0.f}};
#pragma unroll
    for (int kb = 0; kb < 4; ++kb) {
      frag_ab b = *(const frag_ab*)(Wclsf + (size_t)((nb * 4 + kb) * 64 + lane) * 8);
#pragma unroll
      for (int rt = 0; rt < 2; ++rt)
        acc[rt] = __builtin_amdgcn_mfma_f32_16x16x32_bf16(h3[rt][kb], b, acc[rt], 0, 0, 0);
    }
    int col = nb * 16 + lm;
    float bv = bcls[col];
#pragma unroll
    for (int rt = 0; rt < 2; ++rt)
#pragma unroll
      for (int r = 0; r < 4; ++r) {
        int grow = m0 + rt * 16 + lq * 4 + r;
        if (grow < N) out[(long)grow * 64 + col] = acc[rt][r] + bv;
      }
  }
}

extern "C" void kernel_launch(void* const* d_in, const int* in_sizes, int n_in,
                              void* d_out, int out_size, void* d_ws, size_t ws_size,
                              hipStream_t stream) {
  const float* x    = (const float*)d_in[0];
  const void*  ei   = d_in[1];
  const float* W1x  = (const float*)d_in[2];
  const float* b1x  = (const float*)d_in[3];
  const float* W2x  = (const float*)d_in[4];
  const float* b2x  = (const float*)d_in[5];
  const float* W1a  = (const float*)d_in[6];
  const float* b1a  = (const float*)d_in[7];
  const float* W2a  = (const float*)d_in[8];
  const float* b2a  = (const float*)d_in[9];
  const float* Wc   = (const float*)d_in[10];
  const float* bc   = (const float*)d_in[11];
  const float* Wcls = (const float*)d_in[12];
  const float* bcls = (const float*)d_in[13];
  const int N = in_sizes[0] / 64;
  const int E = in_sizes[1] / 2;

  const int NB = (N + 511) >> 9;          // 512 rows per bucket
  const int NBpad = (NB + 63) & ~63;
  const int CH = (E + 255) / 256;

  float* ws = (float*)d_ws;
  long nAlign = (N + 255) & ~255L;
  float* dinv = ws;                                    // N
  int*   rowptr = (int*)(ws + nAlign);                 // N+1
  u16*   xb   = (u16*)(ws + 2 * nAlign + 256);         // N*64 bf16
  u16*   aggb = xb + (long)N * 64;                     // N*64 bf16
  u8*    xq   = (u8*)(aggb + (long)N * 64);            // N*64 fp8
  float* bp   = (float*)(xq + ((long)N * 64 + 255 & ~255L));  // 128
  u16*   W1xf = (u16*)(bp + 128);                      // 8192
  u16*   W1af = W1xf + 8192;                           // 8192
  u16*   Wxpf = W1af + 8192;                           // 16384
  u16*   Wapf = Wxpf + 16384;                          // 16384
  u16*   Wclsf = Wapf + 16384;                         // 8192
  int*   bh   = (int*)(Wclsf + 8192);                  // 256*NBpad
  int*   bstart = bh + 256 * NBpad;                    // NB+1 (+pad)
  u32*   staged = (u32*)(bstart + NB + 64);            // E
  u32*   cols   = staged + E;                          // E
  float* out = (float*)d_out;

  k_bhist_cvt<<<256, 256, 0, stream>>>(ei, E, CH, NB, NBpad, bh, x, xb, xq,
                                       (long)N * 64);
  k_cscan<<<1, 256, 0, stream>>>(bh, bstart, NB, NBpad, E);
  k_partition<<<256, 256, 0, stream>>>(ei, E, CH, NB, NBpad, bh, staged);
  k_csr_bucket<<<NB, 1024, 0, stream>>>(staged, bstart, rowptr, dinv, cols, N, E);
  k_aggregate<<<(N + 7) / 8, 256, 0, stream>>>(rowptr, cols, xb, xq, dinv, aggb, N);
  k_wpack<<<225, 256, 0, stream>>>(W1x, W1a, W2x, W2a, Wc, b2x, b2a, bc, Wcls,
                                   W1xf, W1af, Wxpf, Wapf, Wclsf, bp);
  k_mlp<<<(N + 127) / 128, 256, 0, stream>>>(xb, aggb, W1xf, W1af, b1x, b1a,
                                             Wxpf, Wapf, bp, Wclsf, bcls, out, N);
}